// Round 2
// baseline (365.131 us; speedup 1.0000x reference)
//
#include <hip/hip_runtime.h>

// Embedding gather: out[i, :] = table[indices[i], :]
// VOCAB = 1,000,000 rows, EMBED_DIM = 16 floats (64 B) per row,
// NUM_INDICES = 4,194,304.
//
// Layout: one thread per float4 (16 B) of output -> 4 threads/row.
// Consecutive lanes write consecutive float4s => fully coalesced 1 KB/wave
// stores; the 4 lanes of a row broadcast-read the same index and a
// contiguous 64 B table row.
//
// Round-2 change: per-thread batching for memory-level parallelism.
// The old kernel was a strictly serial idx->table load chain, ONE
// outstanding miss-chain per wave, across 65536 tiny blocks -> latency
// bound (~2 TB/s effective vs 6.5 TB/s demonstrated by the reset fills).
// Now each thread handles K=8 segments: 8 independent index loads are
// issued back-to-back, then 8 independent table loads, then 8 stores.
// MLP per wave: 1 -> 8; grid: 65536 -> 8192 blocks.
// Coalescing per k-step is unchanged (wave reads 16 consecutive int32,
// writes contiguous 1 KB).

typedef float v4f __attribute__((ext_vector_type(4)));

constexpr int K     = 8;    // batched rows per thread (MLP depth)
constexpr int BLOCK = 256;

__global__ void __launch_bounds__(BLOCK)
embed_gather_kernel(const int* __restrict__ indices,
                    const v4f* __restrict__ table4,
                    v4f* __restrict__ out4,
                    int n_rows) {
    const long long nseg = (long long)n_rows * 4;
    const long long base = (long long)blockIdx.x * (BLOCK * K) + threadIdx.x;

    if (base + (long long)(K - 1) * BLOCK < nseg) {
        // Fast path (exact for the bench shape: 16,777,216 / 2048 = 8192 blocks).
        // Phase 1: 8 independent, coalesced index loads.
        int ridx[K];
#pragma unroll
        for (int k = 0; k < K; ++k) {
            long long s = base + (long long)k * BLOCK;
            ridx[k] = indices[s >> 2];
        }
        // BLOCK % 4 == 0 -> the float4-segment within the row is constant.
        const int seg = (int)(base & 3);
        // Phase 2: 8 independent random 16 B table reads (cached path).
        v4f vals[K];
#pragma unroll
        for (int k = 0; k < K; ++k)
            vals[k] = table4[(size_t)ridx[k] * 4 + seg];
        // Phase 3: 8 coalesced nontemporal stores (pure write stream).
#pragma unroll
        for (int k = 0; k < K; ++k)
            __builtin_nontemporal_store(vals[k], out4 + base + (long long)k * BLOCK);
    } else {
        // Tail path (not taken for the bench shape).
        for (int k = 0; k < K; ++k) {
            long long s = base + (long long)k * BLOCK;
            if (s < nseg) {
                int r = indices[s >> 2];
                __builtin_nontemporal_store(table4[(size_t)r * 4 + (s & 3)],
                                            out4 + s);
            }
        }
    }
}

extern "C" void kernel_launch(void* const* d_in, const int* in_sizes, int n_in,
                              void* d_out, int out_size, void* d_ws, size_t ws_size,
                              hipStream_t stream) {
    const int* indices = (const int*)d_in[0];
    const v4f* table4  = (const v4f*)d_in[1];
    v4f*       out4    = (v4f*)d_out;

    int n_rows = in_sizes[0];                         // 4,194,304
    long long nseg = (long long)n_rows * 4;           // one float4 each
    long long per_block = (long long)BLOCK * K;
    int grid = (int)((nseg + per_block - 1) / per_block);

    embed_gather_kernel<<<grid, BLOCK, 0, stream>>>(indices, table4, out4, n_rows);
}